// Round 6
// baseline (44.187 us; speedup 1.0000x reference)
//
#include <hip/hip_runtime.h>
#include <float.h>

#define BATCH   8
#define NPTS    4096
#define THREADS 512
#define NWAVE   8                          // 512/64
#define XTILE   512                        // x-points per block
#define P       8                          // x-points per lane
#define NQ      8                          // y slices per (dir,b,tile)
#define YQ      (NPTS / NQ)                // 512 y per block
#define YW      (YQ / NWAVE)               // 64 y per wave
#define XTILES  (NPTS / XTILE)             // 8
#define NSLOT   (2 * BATCH * NPTS)         // 65536 x-slots
#define TOTAL_BLOCKS (2 * BATCH * XTILES * NQ)   // 1024

__device__ __forceinline__ float min3f(float a, float b, float c) {
    float d;
    asm("v_min3_f32 %0, %1, %2, %3" : "=v"(d) : "v"(a), "v"(b), "v"(c));
    return d;
}

// Prep: transform both clouds to (-2y0,-2y1,-2y2,|y|^2) float4, AoS, so the
// main kernel can stream them through the SCALAR pipe (s_load) instead of
// LDS/VMEM. yt[dir][b][p]; dir0 = B (y for dir0), dir1 = A.
__global__ __launch_bounds__(256) void chamfer_prep(
    const float* __restrict__ A, const float* __restrict__ Bp,
    float4* __restrict__ yt)
{
    const int t = blockIdx.x * 256 + threadIdx.x;    // 16384 threads, 4 pts each
    const int g = t * 4;
    const int dir = g >> 15;
    const int b   = (g >> 12) & 7;
    const int p   = g & 4095;
    const float* src = (dir == 0 ? Bp : A) + ((size_t)b * NPTS + p) * 3;
    const float4* s4 = (const float4*)src;           // p%4==0 -> 16B aligned
    const float4 f0 = s4[0], f1 = s4[1], f2 = s4[2];
    // p0=(f0.x,f0.y,f0.z) p1=(f0.w,f1.x,f1.y) p2=(f1.z,f1.w,f2.x) p3=(f2.y,f2.z,f2.w)
    yt[g + 0] = make_float4(-2.f * f0.x, -2.f * f0.y, -2.f * f0.z,
                            f0.x * f0.x + f0.y * f0.y + f0.z * f0.z);
    yt[g + 1] = make_float4(-2.f * f0.w, -2.f * f1.x, -2.f * f1.y,
                            f0.w * f0.w + f1.x * f1.x + f1.y * f1.y);
    yt[g + 2] = make_float4(-2.f * f1.z, -2.f * f1.w, -2.f * f2.x,
                            f1.z * f1.z + f1.w * f1.w + f2.x * f2.x);
    yt[g + 3] = make_float4(-2.f * f2.y, -2.f * f2.z, -2.f * f2.w,
                            f2.y * f2.y + f2.z * f2.z + f2.w * f2.w);
}

// Block = (dir, batch, x-tile of 512, y-slice of 512). Lane l owns x {l+64p}.
// Wave w streams its 64 transformed y from global via UNIFORM addresses
// (blockIdx + readfirstlane(wave) + loop counter) -> s_load into SGPRs;
// inner loop is pure VALU: per y per x-chain 3 fma (1 SGPR operand each)
// + min3 per 2 y; |y|^2 costs one shared v_mov per y. No LDS in the loop.
__global__ __launch_bounds__(THREADS, 4) void chamfer_min_kernel(
    const float* __restrict__ A, const float* __restrict__ Bp,
    const float4* __restrict__ yt, float* __restrict__ partial)
{
    __shared__ float smin[NWAVE][XTILE];     // 16 KB
    __shared__ float sxs[XTILE];             // 2 KB

    const int bid  = blockIdx.x;
    const int q    = bid & 7;
    const int tile = (bid >> 3) & 7;
    const int b    = (bid >> 6) & 7;
    const int dir  = bid >> 9;
    const int tid  = threadIdx.x;
    const int lane = tid & 63;
    const int wave_u = __builtin_amdgcn_readfirstlane(tid >> 6);  // uniform wave id

    const float* xbase = (dir == 0 ? A : Bp) + (size_t)b * NPTS * 3;

    // ---- 8 x-points per lane into registers ----
    float x0[P], x1[P], x2[P], mn[P];
    #pragma unroll
    for (int p = 0; p < P; ++p) {
        const int xi = tile * XTILE + p * 64 + lane;
        x0[p] = xbase[xi * 3 + 0];
        x1[p] = xbase[xi * 3 + 1];
        x2[p] = xbase[xi * 3 + 2];
        mn[p] = FLT_MAX;
        if (wave_u == 0)
            sxs[p * 64 + lane] = x0[p] * x0[p] + x1[p] * x1[p] + x2[p] * x2[p];
    }

    // ---- main loop: uniform-address stream of 64 y through the scalar pipe ----
    const float4* yw = yt + ((size_t)(dir * BATCH + b) * NPTS) + q * YQ + wave_u * YW;
    #pragma unroll 2
    for (int k = 0; k < YW; k += 2) {
        const float4 ya = yw[k];             // uniform -> s_load, values in SGPRs
        const float4 yb = yw[k + 1];
        #pragma unroll
        for (int p = 0; p < P; ++p) {
            const float da = fmaf(x0[p], ya.x, fmaf(x1[p], ya.y, fmaf(x2[p], ya.z, ya.w)));
            const float db = fmaf(x0[p], yb.x, fmaf(x1[p], yb.y, fmaf(x2[p], yb.z, yb.w)));
            mn[p] = min3f(mn[p], da, db);
        }
    }

    const int wv = tid >> 6;
    #pragma unroll
    for (int p = 0; p < P; ++p)
        smin[wv][p * 64 + lane] = mn[p];
    __syncthreads();

    // ---- per-x slice-partial: 8-way min, add |x|^2, clamp, write ws[g][q] ----
    {
        float m = smin[0][tid];
        #pragma unroll
        for (int w = 1; w < NWAVE; ++w) m = fminf(m, smin[w][tid]);
        const int g = ((dir * BATCH + b) << 12) + tile * XTILE + tid;
        partial[g * NQ + q] = fmaxf(sxs[tid] + m, 0.0f);
    }
}

// Stage 2: 64 blocks x 256 threads, 4 x-slots/thread: min over 8 slices,
// sum within block (fixed-order tree) -> part2[64].
__global__ __launch_bounds__(256) void chamfer_reduce1(
    const float4* __restrict__ pw, float* __restrict__ part2)
{
    __shared__ float r[256];
    const int tid = threadIdx.x;
    float acc = 0.0f;
    #pragma unroll
    for (int j = 0; j < 4; ++j) {
        const int s = blockIdx.x * 1024 + j * 256 + tid;
        const float4 v0 = pw[s * 2 + 0];
        const float4 v1 = pw[s * 2 + 1];
        const float m0 = fminf(fminf(v0.x, v0.y), fminf(v0.z, v0.w));
        const float m1 = fminf(fminf(v1.x, v1.y), fminf(v1.z, v1.w));
        acc += fminf(m0, m1);
    }
    r[tid] = acc;
    __syncthreads();
    #pragma unroll
    for (int s = 128; s > 0; s >>= 1) {
        if (tid < s) r[tid] += r[tid + s];
        __syncthreads();
    }
    if (tid == 0) part2[blockIdx.x] = r[0];
}

// Stage 3: single wave, fixed-order reduce of 64 partials, scale, write scalar.
__global__ __launch_bounds__(64) void chamfer_reduce2(
    const float* __restrict__ part2, float* __restrict__ out)
{
    float v = part2[threadIdx.x];
    #pragma unroll
    for (int off = 32; off > 0; off >>= 1)
        v += __shfl_down(v, off, 64);
    if (threadIdx.x == 0) out[0] = v * (1.0f / (BATCH * NPTS));
}

extern "C" void kernel_launch(void* const* d_in, const int* in_sizes, int n_in,
                              void* d_out, int out_size, void* d_ws, size_t ws_size,
                              hipStream_t stream) {
    const float* A = (const float*)d_in[0];   // coor_recon [8,4096,3]
    const float* B = (const float*)d_in[1];   // pc_gd      [8,4096,3]
    float4* yt     = (float4*)d_ws;                        // 65536 float4 (1 MB)
    float*  partial = (float*)(yt + NSLOT);                // [65536][8] (2 MB)
    float*  part2   = partial + (size_t)NSLOT * NQ;        // [64]
    float* out = (float*)d_out;

    chamfer_prep<<<64, 256, 0, stream>>>(A, B, yt);
    chamfer_min_kernel<<<TOTAL_BLOCKS, THREADS, 0, stream>>>(A, B, yt, partial);
    chamfer_reduce1<<<64, 256, 0, stream>>>((const float4*)partial, part2);
    chamfer_reduce2<<<1, 64, 0, stream>>>(part2, out);
}

// Round 11
// 28.896 us; speedup vs baseline: 1.5292x; 1.5292x over previous
//
#include <hip/hip_runtime.h>
#include <float.h>

typedef float v2f __attribute__((ext_vector_type(2)));

#define BATCH   8
#define NPTS    4096
#define THREADS 512
#define NWAVE   (THREADS / 64)            // 8 waves
#define XTILE   256                       // x-points per block
#define P       4                         // x-points per lane
#define NH      2                         // y halves per (dir,b,tile)
#define YH      (NPTS / NH)               // 2048 y per block
#define NPAIRB  (YH / 2)                  // 1024 staged y-pairs
#define PPW     (NPAIRB / NWAVE)          // 128 pairs per wave
#define NSLOT   (2 * BATCH * NPTS)        // 65536 x-slots
#define BLOCKS_PER_DIR (BATCH * (NPTS / XTILE) * NH)   // 8*16*2 = 256
#define TOTAL_BLOCKS   (2 * BLOCKS_PER_DIR)            // 512

__device__ __forceinline__ float min3f(float a, float b, float c) {
    float d;
    asm("v_min3_f32 %0, %1, %2, %3" : "=v"(d) : "v"(a), "v"(b), "v"(c));
    return d;
}

// Proven r4 structure (28.4 us, absmax 0) + occupancy fix: y split in half per
// block (each block stages a disjoint 2048-y half, 41 KB LDS) -> 512 blocks =
// 2 blocks/CU = 4 waves/SIMD (was 1 block/CU, 2 waves/SIMD, Occ 32%).
// Inner loop unchanged: lane owns 4 x; per y-pair 2 broadcast ds_read_b128 +
// 4x(3 pk_fma + 1 min3). LDS pair-packed:
//   ysAB[k] = (-2y0[2k], -2y0[2k+1], -2y1[2k], -2y1[2k+1])
//   ysCW[k] = (-2y2[2k], -2y2[2k+1], |y[2k]|^2, |y[2k+1]|^2)
// |x|^2 folded after the 8-wave min (translation-invariance of min).
__global__ __launch_bounds__(THREADS) void chamfer_min_kernel(
    const float* __restrict__ A, const float* __restrict__ Bp,
    float* __restrict__ partial)
{
    __shared__ float4 ysAB[NPAIRB];          // 16 KB
    __shared__ float4 ysCW[NPAIRB];          // 16 KB
    __shared__ float  smin[NWAVE][XTILE];    // 8 KB
    __shared__ float  sxs[XTILE];            // 1 KB

    const int bid  = blockIdx.x;
    const int q    = bid & 1;                // y-half
    const int tile = (bid >> 1) & 15;
    const int b    = (bid >> 5) & 7;
    const int dir  = bid >> 8;
    const int tid  = threadIdx.x;
    const int lane = tid & 63;
    const int wave = tid >> 6;

    const float* xbase = (dir == 0 ? A : Bp) + (size_t)b * NPTS * 3;
    const float* ybase = (dir == 0 ? Bp : A) + (size_t)b * NPTS * 3
                         + (size_t)q * YH * 3;

    // ---- stage y-half: thread t handles points 4t..4t+3 = 3 aligned float4 ----
    {
        const float4* yg4 = (const float4*)ybase;
        const float4 f0 = yg4[3 * tid + 0];
        const float4 f1 = yg4[3 * tid + 1];
        const float4 f2 = yg4[3 * tid + 2];
        // p0=(f0.x,f0.y,f0.z) p1=(f0.w,f1.x,f1.y) p2=(f1.z,f1.w,f2.x) p3=(f2.y,f2.z,f2.w)
        const int k0 = 2 * tid;
        ysAB[k0]     = make_float4(-2.f * f0.x, -2.f * f0.w, -2.f * f0.y, -2.f * f1.x);
        ysCW[k0]     = make_float4(-2.f * f0.z, -2.f * f1.y,
                                   f0.x * f0.x + f0.y * f0.y + f0.z * f0.z,
                                   f0.w * f0.w + f1.x * f1.x + f1.y * f1.y);
        ysAB[k0 + 1] = make_float4(-2.f * f1.z, -2.f * f2.y, -2.f * f1.w, -2.f * f2.z);
        ysCW[k0 + 1] = make_float4(-2.f * f2.x, -2.f * f2.w,
                                   f1.z * f1.z + f1.w * f1.w + f2.x * f2.x,
                                   f2.y * f2.y + f2.z * f2.z + f2.w * f2.w);
    }

    // ---- 4 x-points per lane, splatted for packed math ----
    v2f X0[P], X1[P], X2[P];
    float mn[P];
    #pragma unroll
    for (int p = 0; p < P; ++p) {
        const int xi = tile * XTILE + p * 64 + lane;
        const float x0 = xbase[xi * 3 + 0];
        const float x1 = xbase[xi * 3 + 1];
        const float x2 = xbase[xi * 3 + 2];
        X0[p] = (v2f){x0, x0};
        X1[p] = (v2f){x1, x1};
        X2[p] = (v2f){x2, x2};
        mn[p] = FLT_MAX;
        if (wave == 0)
            sxs[p * 64 + lane] = x0 * x0 + x1 * x1 + x2 * x2;
    }
    __syncthreads();

    // ---- main loop: wave scans its 128 y-pairs ----
    const float4* abp = &ysAB[wave * PPW];
    const float4* cwp = &ysCW[wave * PPW];
    #pragma unroll 4
    for (int k = 0; k < PPW; ++k) {
        const float4 ab = abp[k];            // broadcast ds_read_b128
        const float4 cw = cwp[k];
        const v2f Av = (v2f){ab.x, ab.y};
        const v2f Bv = (v2f){ab.z, ab.w};
        const v2f Cv = (v2f){cw.x, cw.y};
        const v2f Wv = (v2f){cw.z, cw.w};
        #pragma unroll
        for (int p = 0; p < P; ++p) {
            const v2f d = __builtin_elementwise_fma(X0[p], Av,
                          __builtin_elementwise_fma(X1[p], Bv,
                          __builtin_elementwise_fma(X2[p], Cv, Wv)));
            mn[p] = min3f(mn[p], d[0], d[1]);
        }
    }

    #pragma unroll
    for (int p = 0; p < P; ++p)
        smin[wave][p * 64 + lane] = mn[p];
    __syncthreads();

    // ---- per-x half-partial: 8-way min, add |x|^2, clamp, write ws[g][q] ----
    if (tid < XTILE) {
        float m = smin[0][tid];
        #pragma unroll
        for (int w = 1; w < NWAVE; ++w) m = fminf(m, smin[w][tid]);
        const int g = ((dir * BATCH + b) << 12) + tile * XTILE + tid;
        partial[g * NH + q] = fmaxf(sxs[tid] + m, 0.0f);
    }
}

// Stage 2: 64 blocks x 256 threads, 4 x-slots/thread: min over the 2 y-halves,
// sum within block (fixed-order tree) -> part2[64].
__global__ __launch_bounds__(256) void chamfer_reduce1(
    const float2* __restrict__ pw, float* __restrict__ part2)
{
    __shared__ float r[256];
    const int tid = threadIdx.x;
    float acc = 0.0f;
    #pragma unroll
    for (int j = 0; j < 4; ++j) {
        const float2 v = pw[blockIdx.x * 1024 + j * 256 + tid];
        acc += fminf(v.x, v.y);
    }
    r[tid] = acc;
    __syncthreads();
    #pragma unroll
    for (int s = 128; s > 0; s >>= 1) {
        if (tid < s) r[tid] += r[tid + s];
        __syncthreads();
    }
    if (tid == 0) part2[blockIdx.x] = r[0];
}

// Stage 3: single wave, fixed-order reduce of 64 partials, scale, write scalar.
__global__ __launch_bounds__(64) void chamfer_reduce2(
    const float* __restrict__ part2, float* __restrict__ out)
{
    float v = part2[threadIdx.x];
    #pragma unroll
    for (int off = 32; off > 0; off >>= 1)
        v += __shfl_down(v, off, 64);
    if (threadIdx.x == 0) out[0] = v * (1.0f / (BATCH * NPTS));
}

extern "C" void kernel_launch(void* const* d_in, const int* in_sizes, int n_in,
                              void* d_out, int out_size, void* d_ws, size_t ws_size,
                              hipStream_t stream) {
    const float* A = (const float*)d_in[0];   // coor_recon [8,4096,3]
    const float* B = (const float*)d_in[1];   // pc_gd      [8,4096,3]
    float* partial = (float*)d_ws;            // [65536][2] half-partials (512 KB)
    float* part2   = partial + (size_t)NSLOT * NH;   // [64]
    float* out = (float*)d_out;

    chamfer_min_kernel<<<TOTAL_BLOCKS, THREADS, 0, stream>>>(A, B, partial);
    chamfer_reduce1<<<64, 256, 0, stream>>>((const float2*)partial, part2);
    chamfer_reduce2<<<1, 64, 0, stream>>>(part2, out);
}